// Round 3
// baseline (229.742 us; speedup 1.0000x reference)
//
#include <hip/hip_runtime.h>

// ASIC_87007447483060 — soft logic-rail update, fused single pass.
// R2: passed, dur 227us; asic_main <78us vs ~30us traffic floor (185 MB).
// R3: 4 px/thread, tg (72% of traffic) as aligned float4 loads.

constexpr int N     = 1024;
constexpr int NP1   = N + 1;           // 1025
constexpr int PLANE = NP1 * NP1;       // 1050625
constexpr int NN    = N * N;

__device__ __forceinline__ float sigmoidf_fast(float t) {
    return __builtin_amdgcn_rcpf(1.0f + __expf(-t));
}

// One thread per 4 consecutive interior pixels (r, c0..c0+3), c0 % 4 == 0
// (rows are 1024 wide so a quad never crosses a row).
// outs scatter: planes 0,1 -> (r,c); planes 2,3 -> (r+1,c+1).
__global__ __launch_bounds__(256) void asic_main(
    const float* __restrict__ x,
    const float* __restrict__ tg,
    const float* __restrict__ rail,
    const int*  __restrict__ mask,
    float* __restrict__ out)
{
    const int tid  = blockIdx.x * 256 + threadIdx.x;   // 262144 threads
    const int pix0 = tid << 2;                          // 4*tid
    const int r    = pix0 >> 10;
    const int c0   = pix0 & (N - 1);
    const float g0 = tg[0];

    // Gather new_inputs for the 4 planes x 4 pixels.
    float u[4][4];
    const int b01 = (r + 1) * NP1 + (c0 + 1);
    const int b23 = r * NP1 + c0;
#pragma unroll
    for (int q = 0; q < 4; ++q) {
        u[0][q] = rail[0 * PLANE + b01 + q];
        u[1][q] = rail[1 * PLANE + b01 + q];
        u[2][q] = rail[2 * PLANE + b23 + q];
        u[3][q] = rail[3 * PLANE + b23 + q];
    }
    if (c0 == 0) u[3][0] = x[r];   // view-write of x into plane 3, col 0

    // Soft-AND factors: F0 = 1-|u|, F1 = 1-|1-u|.
    float F0[4][4], F1[4][4];
#pragma unroll
    for (int j = 0; j < 4; ++j)
#pragma unroll
        for (int q = 0; q < 4; ++q) {
            F0[j][q] = 1.0f - fabsf(u[j][q]);
            F1[j][q] = 1.0f - fabsf(1.0f - u[j][q]);
        }

#pragma unroll
    for (int i = 0; i < 4; ++i) {
        const int o0 = (i == 0) ? 1 : 0;     // others[i], ascending
        const int o1 = (i <= 1) ? 2 : 1;
        const int o2 = (i <= 2) ? 3 : 2;

        // h[b1][b2] = F_{b1}[o1] * F_{b2}[o2], per pixel
        float h00[4], h01[4], h10[4], h11[4];
#pragma unroll
        for (int q = 0; q < 4; ++q) {
            h00[q] = F0[o1][q] * F0[o2][q];
            h01[q] = F0[o1][q] * F1[o2][q];
            h10[q] = F1[o1][q] * F0[o2][q];
            h11[q] = F1[o1][q] * F1[o2][q];
        }

        float s0[4] = {0.f, 0.f, 0.f, 0.f};  // sum_p w_p
        float s1[4] = {0.f, 0.f, 0.f, 0.f};  // sum_p tw_p * w_p
#pragma unroll
        for (int p = 0; p < 8; ++p) {
            // Aligned 16B load: plane base (i*8+p)*NN*4B and pix0*4B are both %16==0.
            const float4 tv =
                *reinterpret_cast<const float4*>(&tg[(i * 8 + p) * NN + pix0]);
            const float tw[4] = { sigmoidf_fast(tv.x), sigmoidf_fast(tv.y),
                                  sigmoidf_fast(tv.z), sigmoidf_fast(tv.w) };
            const int b0 = p >> 2, b1 = (p >> 1) & 1, b2 = p & 1;
#pragma unroll
            for (int q = 0; q < 4; ++q) {
                const float fa = b0 ? F1[o0][q] : F0[o0][q];
                const float hb = b1 ? (b2 ? h11[q] : h10[q])
                                    : (b2 ? h01[q] : h00[q]);
                const float w  = fa * hb;
                s0[q] += w;
                s1[q]  = fmaf(tw[q], w, s1[q]);
            }
        }

        // toggled·w summed = (2u-1)·s1 + (1-u)·s0, then clip, mask, scale.
#pragma unroll
        for (int q = 0; q < 4; ++q) {
            const float A = 2.0f * u[i][q] - 1.0f;
            const float B = 1.0f - u[i][q];
            float acc = fmaf(A, s1[q], B * s0[q]);
            acc = fminf(fmaxf(acc, 0.0f), 1.0f);
            const int flat = (i < 2) ? (i * PLANE + r * NP1 + (c0 + q))
                                     : (i * PLANE + (r + 1) * NP1 + (c0 + q + 1));
            out[flat] = acc * (float)mask[flat] * g0;
        }
    }
}

// Boundary passthrough: 2n+1 cells per plane (8196 total).
// Planes 0,1: row n + col n (rows 0..n-1). Planes 2,3: row 0 + col 0 (rows 1..n).
// Plane 3 col 0 rows 0..n-1 carries x[r].
__global__ __launch_bounds__(256) void asic_boundary(
    const float* __restrict__ x,
    const float* __restrict__ tg,
    const float* __restrict__ rail,
    const int*  __restrict__ mask,
    float* __restrict__ out)
{
    const int per = 2 * N + 1;  // 2049
    const int idx = blockIdx.x * 256 + threadIdx.x;
    if (idx >= 4 * per) return;
    const int plane = idx / per;
    const int k = idx % per;

    int r, c;
    if (plane < 2) {
        if (k <= N) { r = N; c = k; }
        else        { r = k - (N + 1); c = N; }
    } else {
        if (k <= N) { r = 0; c = k; }
        else        { r = k - N; c = 0; }
    }

    const int flat = plane * PLANE + r * NP1 + c;
    float v;
    if (plane == 3 && c == 0 && r < N) v = x[r];
    else                               v = rail[flat];
    out[flat] = v * (float)mask[flat] * tg[0];
}

extern "C" void kernel_launch(void* const* d_in, const int* in_sizes, int n_in,
                              void* d_out, int out_size, void* d_ws, size_t ws_size,
                              hipStream_t stream) {
    const float* x    = (const float*)d_in[0];   // (n,)
    const float* tg   = (const float*)d_in[1];   // (4,8,n,n)
    const float* rail = (const float*)d_in[2];   // (4*(n+1)^2,)
    const int*   mask = (const int*)d_in[3];     // (4*(n+1)^2,)
    float* out = (float*)d_out;                  // (4*(n+1)^2,) f32

    asic_main<<<(NN / 4) / 256, 256, 0, stream>>>(x, tg, rail, mask, out);

    const int nb = 4 * (2 * N + 1);              // 8196
    asic_boundary<<<(nb + 255) / 256, 256, 0, stream>>>(x, tg, rail, mask, out);
}

// Round 5
// 225.184 us; speedup vs baseline: 1.0202x; 1.0202x over previous
//
#include <hip/hip_runtime.h>

// ASIC_87007447483060 — soft logic-rail update, fused single pass.
// R2: 227us total; harness fills/restores ~131-160us of it, ours ~70-95us
//     vs ~29us traffic floor (185 MB).
// R3: float4 tg loads — NEUTRAL (scalar loads were already wave-coalesced;
//     issue count was never the limit).
// R4: nontemporal builtin rejects HIP_vector_type -> use ext_vector_type.
// R5 theory: ours is latency/occupancy-bound. Cut live VGPRs (recompute
//     soft-AND factors per phase), __launch_bounds__(256,5), nontemporal
//     tg loads + out stores, boundary merged into main (1 launch).

constexpr int N     = 1024;
constexpr int NP1   = N + 1;           // 1025
constexpr int PLANE = NP1 * NP1;       // 1050625
constexpr int NN    = N * N;

typedef float floatx4 __attribute__((ext_vector_type(4)));

__device__ __forceinline__ float sigmoidf_fast(float t) {
    return __builtin_amdgcn_rcpf(1.0f + __expf(-t));
}

// 1024 blocks x 256 threads. Each thread owns 4 consecutive interior pixels
// (r, c0..c0+3), c0 % 4 == 0. Threads tid < 8196 additionally handle one
// boundary passthrough cell (disjoint from all main scatter targets).
// Main scatter: planes 0,1 -> (r,c); planes 2,3 -> (r+1,c+1).
__global__ __launch_bounds__(256, 5) void asic_fused(
    const float* __restrict__ x,
    const float* __restrict__ tg,
    const float* __restrict__ rail,
    const int*  __restrict__ mask,
    float* __restrict__ out)
{
    const int tid  = blockIdx.x * 256 + threadIdx.x;   // 262144 threads
    const float g0 = tg[0];

    // ---- boundary passthrough (2n+1 cells per plane, 8196 total) ----
    {
        const int per = 2 * N + 1;  // 2049
        if (tid < 4 * per) {
            const int plane = tid / per;
            const int k = tid % per;
            int r, c;
            if (plane < 2) {                    // row n + col n (rows 0..n-1)
                if (k <= N) { r = N; c = k; }
                else        { r = k - (N + 1); c = N; }
            } else {                            // row 0 + col 0 (rows 1..n)
                if (k <= N) { r = 0; c = k; }
                else        { r = k - N; c = 0; }
            }
            const int flat = plane * PLANE + r * NP1 + c;
            float v = (plane == 3 && c == 0 && r < N) ? x[r] : rail[flat];
            out[flat] = v * (float)mask[flat] * g0;
        }
    }

    // ---- main: 4 pixels per thread ----
    const int pix0 = tid << 2;
    const int r    = pix0 >> 10;
    const int c0   = pix0 & (N - 1);

    // Gather new_inputs (persistent: 16 VGPRs).
    float u[4][4];
    const int b01 = (r + 1) * NP1 + (c0 + 1);
    const int b23 = r * NP1 + c0;
#pragma unroll
    for (int q = 0; q < 4; ++q) {
        u[0][q] = rail[0 * PLANE + b01 + q];
        u[1][q] = rail[1 * PLANE + b01 + q];
        u[2][q] = rail[2 * PLANE + b23 + q];
        u[3][q] = rail[3 * PLANE + b23 + q];
    }
    if (c0 == 0) u[3][0] = x[r];   // view-write of x into plane 3, col 0

#pragma unroll
    for (int i = 0; i < 4; ++i) {
        const int o0 = (i == 0) ? 1 : 0;     // others[i], ascending
        const int o1 = (i <= 1) ? 2 : 1;
        const int o2 = (i <= 2) ? 3 : 2;

        // Soft-AND factors for this phase only (recomputed -> fewer live regs).
        float A0[4], A1[4], B0[4], B1[4], C0[4], C1[4];
#pragma unroll
        for (int q = 0; q < 4; ++q) {
            A0[q] = 1.0f - fabsf(u[o0][q]);  A1[q] = 1.0f - fabsf(1.0f - u[o0][q]);
            B0[q] = 1.0f - fabsf(u[o1][q]);  B1[q] = 1.0f - fabsf(1.0f - u[o1][q]);
            C0[q] = 1.0f - fabsf(u[o2][q]);  C1[q] = 1.0f - fabsf(1.0f - u[o2][q]);
        }

        float s0[4] = {0.f, 0.f, 0.f, 0.f};   // sum_p w_p
        float s1[4] = {0.f, 0.f, 0.f, 0.f};   // sum_p tw_p * w_p
#pragma unroll
        for (int p = 0; p < 8; ++p) {
            // Streaming (nontemporal) aligned 16B load of 4 gate values.
            const floatx4 tv = __builtin_nontemporal_load(
                reinterpret_cast<const floatx4*>(&tg[(i * 8 + p) * NN + pix0]));
            const float tw[4] = { sigmoidf_fast(tv.x), sigmoidf_fast(tv.y),
                                  sigmoidf_fast(tv.z), sigmoidf_fast(tv.w) };
            const int b0 = p >> 2, b1 = (p >> 1) & 1, b2 = p & 1;
#pragma unroll
            for (int q = 0; q < 4; ++q) {
                const float w = (b0 ? A1[q] : A0[q]) *
                                (b1 ? B1[q] : B0[q]) *
                                (b2 ? C1[q] : C0[q]);
                s0[q] += w;
                s1[q]  = fmaf(tw[q], w, s1[q]);
            }
        }

        // sum_p toggled_p w_p = (2u-1) s1 + (1-u) s0, clip, mask, scale.
#pragma unroll
        for (int q = 0; q < 4; ++q) {
            const float A = 2.0f * u[i][q] - 1.0f;
            const float B = 1.0f - u[i][q];
            float acc = fmaf(A, s1[q], B * s0[q]);
            acc = fminf(fmaxf(acc, 0.0f), 1.0f);
            const int flat = (i < 2) ? (i * PLANE + r * NP1 + (c0 + q))
                                     : (i * PLANE + (r + 1) * NP1 + (c0 + q + 1));
            __builtin_nontemporal_store(acc * (float)mask[flat] * g0, &out[flat]);
        }
    }
}

extern "C" void kernel_launch(void* const* d_in, const int* in_sizes, int n_in,
                              void* d_out, int out_size, void* d_ws, size_t ws_size,
                              hipStream_t stream) {
    const float* x    = (const float*)d_in[0];   // (n,)
    const float* tg   = (const float*)d_in[1];   // (4,8,n,n)
    const float* rail = (const float*)d_in[2];   // (4*(n+1)^2,)
    const int*   mask = (const int*)d_in[3];     // (4*(n+1)^2,)
    float* out = (float*)d_out;                  // (4*(n+1)^2,) f32

    asic_fused<<<(NN / 4) / 256, 256, 0, stream>>>(x, tg, rail, mask, out);
}